// Round 7
// baseline (291.164 us; speedup 1.0000x reference)
//
#include <hip/hip_runtime.h>

#define NN 4096
#define NE 131072
#define CH 256
#define KSEL 2048

// ---------- out-degree count ----------
__global__ void count_edges(const int* __restrict__ ei, int* __restrict__ rowcnt) {
    int e = blockIdx.x * blockDim.x + threadIdx.x;
    if (e < NE) atomicAdd(&rowcnt[ei[e]], 1);
}

// ---------- exclusive prefix sum of cnt[4096] -> ptr[4097] (single block) ----------
__global__ __launch_bounds__(256) void prefix4096(const int* __restrict__ cnt,
                                                  int* __restrict__ ptr) {
    __shared__ int psum[256];
    int t = threadIdx.x;
    int loc[16];
    int s = 0;
    #pragma unroll
    for (int i = 0; i < 16; i++) { loc[i] = s; s += cnt[t * 16 + i]; }
    psum[t] = s;
    __syncthreads();
    if (t == 0) {
        int run = 0;
        for (int i = 0; i < 256; i++) { int v = psum[i]; psum[i] = run; run += v; }
        ptr[4096] = run;
    }
    __syncthreads();
    int off = psum[t];
    #pragma unroll
    for (int i = 0; i < 16; i++) ptr[t * 16 + i] = off + loc[i];
}

// ---------- scatter edges into CSR colidx (full graph, targets = node ids) ----------
__global__ void scatter_edges(const int* __restrict__ ei, const int* __restrict__ rowptr,
                              int* __restrict__ cursor, int* __restrict__ colidx) {
    int e = blockIdx.x * blockDim.x + threadIdx.x;
    if (e < NE) {
        int r = ei[e];
        int p = atomicAdd(&cursor[r], 1);
        colidx[rowptr[r] + p] = ei[NE + e];
    }
}

// ---------- d1 = float(rowcnt) ----------
__global__ void i2f(const int* __restrict__ rowcnt, float* __restrict__ d1) {
    int i = blockIdx.x * blockDim.x + threadIdx.x;
    d1[i] = (float)rowcnt[i];
}

// ---------- sparse matvec via edge list: vout[row] += vin[col] ----------
__global__ void spmv_edge(const int* __restrict__ ei, const float* __restrict__ vin,
                          float* __restrict__ vout) {
    int e = blockIdx.x * blockDim.x + threadIdx.x;
    if (e < NE) atomicAdd(&vout[ei[e]], vin[ei[NE + e]]);
}

// ---------- score = tanh(pw0 * (x . transform) + pw1 * degree) ----------
__global__ void score_kernel(const float* __restrict__ x, const float* __restrict__ tr,
                             const float* __restrict__ d1, const float* __restrict__ d2,
                             const float* __restrict__ d3, const float* __restrict__ fw,
                             const float* __restrict__ pw, float* __restrict__ score) {
    int gtid = blockIdx.x * blockDim.x + threadIdx.x;
    int node = gtid >> 6;
    int lane = gtid & 63;
    if (node >= NN) return;
    const float* xr = x + (size_t)node * CH;
    float s = 0.f;
    #pragma unroll
    for (int q = 0; q < CH; q += 64) s += xr[q + lane] * tr[q + lane];
    #pragma unroll
    for (int off = 32; off > 0; off >>= 1) s += __shfl_down(s, off);
    if (lane == 0) {
        float deg = fw[0] + fw[1] * d1[node] + fw[2] * d2[node] + fw[3] * d3[node];
        score[node] = tanhf(pw[0] * s + pw[1] * deg);
    }
}

// ---------- stable descending argsort rank; writes rnk for ALL nodes ----------
// rank[i] = #{j : s[j] > s[i]} + #{j < i : s[j] == s[i]}  (== jnp stable argsort(-s))
__global__ __launch_bounds__(256) void rank_kernel(const float* __restrict__ score,
                                                   int* __restrict__ rnk,
                                                   int* __restrict__ perm,
                                                   float* __restrict__ score_perm,
                                                   float* __restrict__ out_perm,
                                                   float* __restrict__ out_score) {
    __shared__ int wsum[4];
    int i = blockIdx.x;
    int t = threadIdx.x;
    float si = score[i];
    int cnt = 0;
    #pragma unroll
    for (int it = 0; it < NN / 4 / 256; it++) {
        int j4 = it * 256 + t;
        float4 s4 = reinterpret_cast<const float4*>(score)[j4];
        int j = j4 * 4;
        cnt += (int)((s4.x > si) | ((s4.x == si) & (j + 0 < i)));
        cnt += (int)((s4.y > si) | ((s4.y == si) & (j + 1 < i)));
        cnt += (int)((s4.z > si) | ((s4.z == si) & (j + 2 < i)));
        cnt += (int)((s4.w > si) | ((s4.w == si) & (j + 3 < i)));
    }
    #pragma unroll
    for (int off = 32; off > 0; off >>= 1) cnt += __shfl_down(cnt, off);
    if ((t & 63) == 0) wsum[t >> 6] = cnt;
    __syncthreads();
    if (t == 0) {
        int r = wsum[0] + wsum[1] + wsum[2] + wsum[3];
        rnk[i] = r;
        if (r < KSEL) {
            perm[r] = i;
            score_perm[r] = si;
            out_perm[r] = (float)i;
            out_score[r] = si;
        }
    }
}

// ---------- selected-CSR: edges (u,v) with rnk[v]<K, target stored as rnk[v] ----------
__global__ void sel_count(const int* __restrict__ ei, const int* __restrict__ rnk,
                          int* __restrict__ cnt_sel) {
    int e = blockIdx.x * blockDim.x + threadIdx.x;
    if (e < NE) {
        if (rnk[ei[NE + e]] < KSEL) atomicAdd(&cnt_sel[ei[e]], 1);
    }
}

__global__ void sel_scatter(const int* __restrict__ ei, const int* __restrict__ rnk,
                            const int* __restrict__ rowptr_sel, int* __restrict__ cursor_sel,
                            int* __restrict__ colidx_sel) {
    int e = blockIdx.x * blockDim.x + threadIdx.x;
    if (e < NE) {
        int rv = rnk[ei[NE + e]];
        if (rv < KSEL) {
            int u = ei[e];
            int p = atomicAdd(&cursor_sel[u], 1);
            colidx_sel[rowptr_sel[u] + p] = rv;
        }
    }
}

// ===== fused M_pool: one block per output row r =====
// G[k] = w3*A2[pr,k] + w2*A[pr,k] + w1*delta(k,pr)   (built in LDS, exact halves)
// M_pool[r,c] = sum_k G[k]*A[k,pc] + w0*delta(r,c)   (scatter via selected CSR)
__global__ __launch_bounds__(256) void fused_mpool(const int* __restrict__ rowptr,
                                                   const int* __restrict__ colidx,
                                                   const int* __restrict__ rowptr_sel,
                                                   const int* __restrict__ colidx_sel,
                                                   const int* __restrict__ perm,
                                                   const float* __restrict__ fw,
                                                   float* __restrict__ Mpool) {
    __shared__ float acc[NN];     // 16 KB: G row over all k
    __shared__ float mrow[KSEL];  // 8 KB:  output row
    int t = threadIdx.x;
    int r = blockIdx.x;
    int pr = perm[r];
    #pragma unroll
    for (int i = t; i < NN / 4; i += 256)
        *(float4*)&acc[i * 4] = float4{0.f, 0.f, 0.f, 0.f};
    #pragma unroll
    for (int i = t; i < KSEL / 4; i += 256)
        *(float4*)&mrow[i * 4] = float4{0.f, 0.f, 0.f, 0.f};
    __syncthreads();
    float w0 = fw[0], w1 = fw[1], w2 = fw[2], w3 = fw[3];
    int s = rowptr[pr], e = rowptr[pr + 1];
    int wave = t >> 6, lane = t & 63;
    // w3 * A2[pr,:]: all 2-paths pr -> k -> v  (multiplicity via duplicate entries)
    for (int i = s + wave; i < e; i += 4) {
        int k = colidx[i];
        int ks = rowptr[k], ke = rowptr[k + 1];
        for (int j = ks + lane; j < ke; j += 64)
            atomicAdd(&acc[colidx[j]], w3);
    }
    // w2 * A[pr,:]
    for (int i = s + t; i < e; i += 256)
        atomicAdd(&acc[colidx[i]], w2);
    if (t == 0) atomicAdd(&acc[pr], w1);
    __syncthreads();
    // mrow[c] += acc[k] * A[k, pc]  via selected CSR (targets pre-mapped to ranks)
    for (int k = t; k < NN; k += 256) {
        float coeff = acc[k];
        if (coeff != 0.f) {
            int ks = rowptr_sel[k], ke = rowptr_sel[k + 1];
            for (int j = ks; j < ke; j++)
                atomicAdd(&mrow[colidx_sel[j]], coeff);
        }
    }
    __syncthreads();
    if (t == 0) mrow[r] += w0;
    __syncthreads();
    #pragma unroll
    for (int i = t; i < KSEL / 4; i += 256)
        *(float4*)(&Mpool[(size_t)r * KSEL + i * 4]) = *(const float4*)&mrow[i * 4];
}

// ---------- x_out = x[perm] * score[perm] ----------
__global__ void xout_kernel(const float* __restrict__ x, const int* __restrict__ perm,
                            const float* __restrict__ score_perm, float* __restrict__ out) {
    int idx = blockIdx.x * blockDim.x + threadIdx.x;
    int r = idx >> 8;
    out[idx] = x[(size_t)perm[r] * CH + (idx & 255)] * score_perm[r];
}

extern "C" void kernel_launch(void* const* d_in, const int* in_sizes, int n_in,
                              void* d_out, int out_size, void* d_ws, size_t ws_size,
                              hipStream_t stream) {
    const float* x  = (const float*)d_in[0];
    const int*   ei = (const int*)d_in[1];
    const float* tr = (const float*)d_in[2];
    const float* fw = (const float*)d_in[3];
    const float* pw = (const float*)d_in[4];

    float* out       = (float*)d_out;
    float* out_x     = out;
    float* out_M     = out + (size_t)KSEL * CH;
    float* out_perm  = out_M + (size_t)KSEL * KSEL;
    float* out_score = out_perm + KSEL;

    char* ws = (char*)d_ws;
    int*   rowcnt     = (int*)(ws);            // 16KB (zeroed block start)
    int*   cursor     = (int*)(ws + 16384);    // 16KB
    int*   cnt_sel    = (int*)(ws + 32768);    // 16KB
    int*   cursor_sel = (int*)(ws + 49152);    // 16KB
    float* d2         = (float*)(ws + 65536);  // 16KB
    float* d3         = (float*)(ws + 81920);  // 16KB (zeroed block end)
    float* d1         = (float*)(ws + 98304);
    float* score      = (float*)(ws + 114688);
    int*   rnk        = (int*)(ws + 131072);
    int*   perm       = (int*)(ws + 147456);   // 8KB
    float* score_perm = (float*)(ws + 155648); // 8KB
    int*   rowptr     = (int*)(ws + 163840);   // 4097 ints (32KB slot)
    int*   rowptr_sel = (int*)(ws + 196608);   // 4097 ints (32KB slot)
    int*   colidx     = (int*)(ws + 229376);   // 512KB
    int*   colidx_sel = (int*)(ws + 753664);   // 512KB

    (void)hipMemsetAsync(rowcnt, 0, 98304, stream);  // rowcnt..d3

    count_edges<<<NE / 256, 256, 0, stream>>>(ei, rowcnt);
    prefix4096<<<1, 256, 0, stream>>>(rowcnt, rowptr);
    scatter_edges<<<NE / 256, 256, 0, stream>>>(ei, rowptr, cursor, colidx);
    i2f<<<NN / 256, 256, 0, stream>>>(rowcnt, d1);
    spmv_edge<<<NE / 256, 256, 0, stream>>>(ei, d1, d2);   // d2 = rowsum(A^2)
    spmv_edge<<<NE / 256, 256, 0, stream>>>(ei, d2, d3);   // d3 = rowsum(A^3)
    score_kernel<<<(NN * 64) / 256, 256, 0, stream>>>(x, tr, d1, d2, d3, fw, pw, score);
    rank_kernel<<<NN, 256, 0, stream>>>(score, rnk, perm, score_perm, out_perm, out_score);
    sel_count<<<NE / 256, 256, 0, stream>>>(ei, rnk, cnt_sel);
    prefix4096<<<1, 256, 0, stream>>>(cnt_sel, rowptr_sel);
    sel_scatter<<<NE / 256, 256, 0, stream>>>(ei, rnk, rowptr_sel, cursor_sel, colidx_sel);
    fused_mpool<<<KSEL, 256, 0, stream>>>(rowptr, colidx, rowptr_sel, colidx_sel, perm, fw, out_M);
    xout_kernel<<<(KSEL * CH) / 256, 256, 0, stream>>>(x, perm, score_perm, out_x);
}